// Round 2
// baseline (29995.215 us; speedup 1.0000x reference)
//
#include <hip/hip_runtime.h>
#include <cstddef>

#define DEV __device__ __forceinline__

constexpr int B   = 16;
constexpr int S   = 128;
constexpr int T   = 128;
constexpr int H   = 512;
constexpr int LAY = 2;
constexpr int V   = 32000;
constexpr int CAT = 64;
constexpr int SOS = 3;

DEV float sigf(float x) { return 1.0f / (1.0f + expf(-x)); }

DEV float wave_max64(float v) {
  for (int o = 32; o > 0; o >>= 1) v = fmaxf(v, __shfl_down(v, o));
  return v;
}
DEV float wave_sum64(float v) {
  for (int o = 32; o > 0; o >>= 1) v += __shfl_down(v, o);
  return v;
}

// ---------------- embeddings ----------------
__global__ __launch_bounds__(256) void k_embed_enc(const int* __restrict__ inp,
                                                   const float* __restrict__ emb,
                                                   float* __restrict__ xemb) {
  int i = blockIdx.x * 256 + threadIdx.x;           // over S*B*(H/4)
  if (i >= S * B * (H / 4)) return;
  int h4 = i & 127;
  int sb = i >> 7;                                   // s*16+b
  int b = sb & 15, s = sb >> 4;
  int tok = inp[b * S + s];
  ((float4*)xemb)[i] = ((const float4*)emb)[(size_t)tok * 128 + h4];
}

__global__ __launch_bounds__(256) void k_embed_dec(const int* __restrict__ outtok,
                                                   const float* __restrict__ emb,
                                                   float* __restrict__ demb) {
  int i = blockIdx.x * 256 + threadIdx.x;           // over T*B*(H/4)
  if (i >= T * B * (H / 4)) return;
  int h4 = i & 127;
  int tb = i >> 7;                                   // t*16+b
  int b = tb & 15, t = tb >> 4;
  int tok = (t == 0) ? SOS : outtok[b * T + (t - 1)];
  ((float4*)demb)[i] = ((const float4*)emb)[(size_t)tok * 128 + h4];
}

__global__ __launch_bounds__(256) void k_catemb(const int* __restrict__ catvec,
                                                const float* __restrict__ emb,
                                                float* __restrict__ catenc) {
  int i = blockIdx.x * 256 + threadIdx.x;           // over B*CAT*(H/4)
  if (i >= B * CAT * (H / 4)) return;
  int h4 = i & 127;
  int bk = i >> 7;                                   // b*64+k
  int tok = catvec[bk];
  ((float4*)catenc)[i] = ((const float4*)emb)[(size_t)tok * 128 + h4];
}

// ---------------- generic GEMM: C[m][n] = A[m][:K] . W[n][:K] + bias[n] ----------------
// OUTMODE 0: C[m*ldc+n].  OUTMODE 1: m = t*16+b -> C[(b*T+t)*V + n]  (logits layout)
template <int OUTMODE>
__global__ __launch_bounds__(256) void k_gemm(const float* __restrict__ A, int lda,
                                              const float* __restrict__ W, int ldw,
                                              const float* __restrict__ bias,
                                              float* __restrict__ C, int ldc,
                                              int M, int N, int K) {
  __shared__ float As[16][68];
  __shared__ float Ws[16][68];
  int tid = threadIdx.x;
  int tx = tid & 15, ty = tid >> 4;
  int bn = blockIdx.x << 6;
  int bm = blockIdx.y << 6;
  int la = tid >> 2;               // 0..63
  int lk = (tid & 3) << 2;         // 0,4,8,12
  float acc[4][4] = {};
  for (int k0 = 0; k0 < K; k0 += 16) {
    float4 av = make_float4(0.f, 0.f, 0.f, 0.f);
    if (bm + la < M) av = *(const float4*)(A + (size_t)(bm + la) * lda + k0 + lk);
    float4 wv = *(const float4*)(W + (size_t)(bn + la) * ldw + k0 + lk);
    As[lk + 0][la] = av.x; As[lk + 1][la] = av.y; As[lk + 2][la] = av.z; As[lk + 3][la] = av.w;
    Ws[lk + 0][la] = wv.x; Ws[lk + 1][la] = wv.y; Ws[lk + 2][la] = wv.z; Ws[lk + 3][la] = wv.w;
    __syncthreads();
#pragma unroll
    for (int kk = 0; kk < 16; ++kk) {
      float4 a4 = *(const float4*)&As[kk][ty << 2];
      float4 w4 = *(const float4*)&Ws[kk][tx << 2];
      acc[0][0] += a4.x * w4.x; acc[0][1] += a4.x * w4.y; acc[0][2] += a4.x * w4.z; acc[0][3] += a4.x * w4.w;
      acc[1][0] += a4.y * w4.x; acc[1][1] += a4.y * w4.y; acc[1][2] += a4.y * w4.z; acc[1][3] += a4.y * w4.w;
      acc[2][0] += a4.z * w4.x; acc[2][1] += a4.z * w4.y; acc[2][2] += a4.z * w4.z; acc[2][3] += a4.z * w4.w;
      acc[3][0] += a4.w * w4.x; acc[3][1] += a4.w * w4.y; acc[3][2] += a4.w * w4.z; acc[3][3] += a4.w * w4.w;
    }
    __syncthreads();
  }
  int n0 = bn + (tx << 2);
  float4 bv = make_float4(0.f, 0.f, 0.f, 0.f);
  if (bias) bv = *(const float4*)(bias + n0);
#pragma unroll
  for (int i = 0; i < 4; ++i) {
    int m = bm + (ty << 2) + i;
    if (m < M) {
      float4 r;
      r.x = acc[i][0] + bv.x; r.y = acc[i][1] + bv.y;
      r.z = acc[i][2] + bv.z; r.w = acc[i][3] + bv.w;
      if (OUTMODE == 0) {
        *(float4*)(C + (size_t)m * ldc + n0) = r;
      } else {
        size_t row = (size_t)(m & 15) * T + (m >> 4);
        *(float4*)(C + row * V + n0) = r;
      }
    }
  }
}

// ---------------- encoder recurrent step (both dirs in one launch) ----------------
// xW: [2048][2048] row s*16+b, col d*1024+c (bias included)
// Whh: [2][1024][256] for this layer; hping: [2][16][512]; cbuf: [16][512]
__global__ __launch_bounds__(256) void k_enc_step(const float* __restrict__ xW,
                                                  const float* __restrict__ Whh,
                                                  float* __restrict__ hping,
                                                  float* __restrict__ cbuf,
                                                  float* __restrict__ y,
                                                  float* __restrict__ hFin,
                                                  float* __restrict__ cFin, int tt) {
  __shared__ float hs[16][256];
  __shared__ float gl[16][4][16];
  int tid = threadIdx.x;
  int d = blockIdx.x & 1;
  int j0 = (blockIdx.x >> 1) << 4;
  int s = d ? (S - 1 - tt) : tt;
  int par = tt & 1;
  const float* hin = hping + par * 8192;
  float* hout = hping + (par ^ 1) * 8192;
  for (int i = tid; i < 4096; i += 256) {
    int r = i >> 8, jj = i & 255;
    hs[r][jj] = hin[r * 512 + (d << 8) + jj];
  }
  __syncthreads();
  {
    int jl = tid & 15;
    int g = (tid >> 4) & 3;
    int rb = tid >> 6;                 // 0..3 -> rows rb, rb+4, rb+8, rb+12
    int c = (g << 8) + j0 + jl;        // gate col in [0,1024)
    const float* wrow = Whh + ((size_t)(d * 1024 + c)) * 256;
    const float* xrow = xW + (size_t)(s * 16) * 2048 + d * 1024 + c;
    float a0 = xrow[(size_t)rb * 2048];
    float a1 = xrow[(size_t)(rb + 4) * 2048];
    float a2 = xrow[(size_t)(rb + 8) * 2048];
    float a3 = xrow[(size_t)(rb + 12) * 2048];
#pragma unroll 4
    for (int k = 0; k < 256; k += 4) {
      float4 w = *(const float4*)(wrow + k);
      float4 x0 = *(const float4*)&hs[rb][k];
      float4 x1 = *(const float4*)&hs[rb + 4][k];
      float4 x2 = *(const float4*)&hs[rb + 8][k];
      float4 x3 = *(const float4*)&hs[rb + 12][k];
      a0 += x0.x * w.x + x0.y * w.y + x0.z * w.z + x0.w * w.w;
      a1 += x1.x * w.x + x1.y * w.y + x1.z * w.z + x1.w * w.w;
      a2 += x2.x * w.x + x2.y * w.y + x2.z * w.z + x2.w * w.w;
      a3 += x3.x * w.x + x3.y * w.y + x3.z * w.z + x3.w * w.w;
    }
    gl[rb][g][jl] = a0;
    gl[rb + 4][g][jl] = a1;
    gl[rb + 8][g][jl] = a2;
    gl[rb + 12][g][jl] = a3;
  }
  __syncthreads();
  {
    int r = tid >> 4, jl = tid & 15, j = j0 + jl;
    float ii = gl[r][0][jl], ff = gl[r][1][jl], gg = gl[r][2][jl], oo = gl[r][3][jl];
    int idx = r * 512 + (d << 8) + j;
    float cn = sigf(ff) * cbuf[idx] + sigf(ii) * tanhf(gg);
    float hn = sigf(oo) * tanhf(cn);
    cbuf[idx] = cn;
    hout[idx] = hn;
    y[(size_t)(s * 16 + r) * 512 + (d << 8) + j] = hn;
    if (tt == S - 1) { hFin[idx] = hn; cFin[idx] = cn; }
  }
}

// ---------------- decoder init copy ----------------
__global__ __launch_bounds__(256) void k_init_dec(const float* __restrict__ h0all,
                                                  const float* __restrict__ c0all,
                                                  float* __restrict__ h0buf,
                                                  float* __restrict__ h1buf,
                                                  float* __restrict__ cp0,
                                                  float* __restrict__ cp1) {
  int i = blockIdx.x * 256 + threadIdx.x;
  if (i < 8192) {
    h0buf[i] = h0all[i];
    h1buf[i] = h0all[8192 + i];
    cp0[i] = c0all[i];
    cp1[i] = c0all[8192 + i];
  }
}

// ---------------- decoder step kernels ----------------
// K1: gates0 = dtW[t] + op@Wih0[:,512:]^T + h0@Whh0^T
__global__ __launch_bounds__(256) void k_dec1(const float* __restrict__ dtW,
                                              const float* __restrict__ Wih0,
                                              const float* __restrict__ Whh0,
                                              const float* __restrict__ opPrev,
                                              const float* __restrict__ h0in,
                                              float* __restrict__ gates0, int t) {
  __shared__ float opl[16][512];
  __shared__ float hl[16][512];
  int tid = threadIdx.x;
  for (int i = tid; i < 8192; i += 256) {
    opl[i >> 9][i & 511] = opPrev[i];
    hl[i >> 9][i & 511] = h0in[i];
  }
  __syncthreads();
  int c = blockIdx.x * 32 + (tid & 31);
  int rb = tid >> 5;                          // rows rb, rb+8
  const float* wi = Wih0 + (size_t)c * 1024 + 512;
  const float* wh = Whh0 + (size_t)c * 512;
  float a0 = dtW[(size_t)(t * 16 + rb) * 2048 + c];
  float a1 = dtW[(size_t)(t * 16 + rb + 8) * 2048 + c];
#pragma unroll 4
  for (int k = 0; k < 512; k += 4) {
    float4 w = *(const float4*)(wi + k);
    float4 x0 = *(const float4*)&opl[rb][k];
    float4 x1 = *(const float4*)&opl[rb + 8][k];
    a0 += x0.x * w.x + x0.y * w.y + x0.z * w.z + x0.w * w.w;
    a1 += x1.x * w.x + x1.y * w.y + x1.z * w.z + x1.w * w.w;
  }
#pragma unroll 4
  for (int k = 0; k < 512; k += 4) {
    float4 w = *(const float4*)(wh + k);
    float4 x0 = *(const float4*)&hl[rb][k];
    float4 x1 = *(const float4*)&hl[rb + 8][k];
    a0 += x0.x * w.x + x0.y * w.y + x0.z * w.z + x0.w * w.w;
    a1 += x1.x * w.x + x1.y * w.y + x1.z * w.z + x1.w * w.w;
  }
  gates0[rb * 2048 + c] = a0;
  gates0[(rb + 8) * 2048 + c] = a1;
}

// K2: LSTM0 update (redundant per block; block0 persists) + gates1
__global__ __launch_bounds__(256) void k_dec2(float* __restrict__ cping0,
                                              const float* __restrict__ gates0,
                                              const float* __restrict__ Wih1,
                                              const float* __restrict__ Whh1,
                                              const float* __restrict__ b1,
                                              const float* __restrict__ h1in,
                                              float* __restrict__ gates1,
                                              float* __restrict__ h0buf, int t) {
  __shared__ float h0n[16][512];
  __shared__ float h1s[16][512];
  int tid = threadIdx.x;
  int par = t & 1;
  const float* cIn = cping0 + par * 8192;
  float* cOut = cping0 + (par ^ 1) * 8192;
  bool w0 = (blockIdx.x == 0);
  for (int i = tid; i < 8192; i += 256) {
    int r = i >> 9, j = i & 511;
    const float* g = gates0 + r * 2048 + j;
    float ii = g[0], ff = g[512], gg = g[1024], oo = g[1536];
    float cn = sigf(ff) * cIn[i] + sigf(ii) * tanhf(gg);
    float hn = sigf(oo) * tanhf(cn);
    h0n[r][j] = hn;
    h1s[r][j] = h1in[i];
    if (w0) { cOut[i] = cn; h0buf[i] = hn; }
  }
  __syncthreads();
  int c = blockIdx.x * 32 + (tid & 31);
  int rb = tid >> 5;
  const float* wi = Wih1 + (size_t)c * 512;
  const float* wh = Whh1 + (size_t)c * 512;
  float a0 = b1[c], a1 = b1[c];
#pragma unroll 4
  for (int k = 0; k < 512; k += 4) {
    float4 w = *(const float4*)(wi + k);
    float4 x0 = *(const float4*)&h0n[rb][k];
    float4 x1 = *(const float4*)&h0n[rb + 8][k];
    a0 += x0.x * w.x + x0.y * w.y + x0.z * w.z + x0.w * w.w;
    a1 += x1.x * w.x + x1.y * w.y + x1.z * w.z + x1.w * w.w;
  }
#pragma unroll 4
  for (int k = 0; k < 512; k += 4) {
    float4 w = *(const float4*)(wh + k);
    float4 x0 = *(const float4*)&h1s[rb][k];
    float4 x1 = *(const float4*)&h1s[rb + 8][k];
    a0 += x0.x * w.x + x0.y * w.y + x0.z * w.z + x0.w * w.w;
    a1 += x1.x * w.x + x1.y * w.y + x1.z * w.z + x1.w * w.w;
  }
  gates1[rb * 2048 + c] = a0;
  gates1[(rb + 8) * 2048 + c] = a1;
}

// K3: LSTM1 update (block0 persists) + q and catq
__global__ __launch_bounds__(256) void k_dec3(float* __restrict__ cping1,
                                              const float* __restrict__ gates1,
                                              const float* __restrict__ linin,
                                              const float* __restrict__ wmix,
                                              const float* __restrict__ catqpre,
                                              float* __restrict__ h1buf,
                                              float* __restrict__ q,
                                              float* __restrict__ catq, int t) {
  __shared__ float h1n[16][512];
  int tid = threadIdx.x;
  int par = t & 1;
  const float* cIn = cping1 + par * 8192;
  float* cOut = cping1 + (par ^ 1) * 8192;
  bool w0 = (blockIdx.x == 0);
  for (int i = tid; i < 8192; i += 256) {
    int r = i >> 9, j = i & 511;
    const float* g = gates1 + r * 2048 + j;
    float ii = g[0], ff = g[512], gg = g[1024], oo = g[1536];
    float cn = sigf(ff) * cIn[i] + sigf(ii) * tanhf(gg);
    float hn = sigf(oo) * tanhf(cn);
    h1n[r][j] = hn;
    if (w0) { cOut[i] = cn; h1buf[i] = hn; }
  }
  __syncthreads();
  int half = blockIdx.x >> 4;
  int c = (blockIdx.x & 15) * 32 + (tid & 31);
  int rb = tid >> 5;
  if (half == 0) {
    const float* w = linin + (size_t)c * 512;
    float a0 = 0.f, a1 = 0.f;
#pragma unroll 4
    for (int k = 0; k < 512; k += 4) {
      float4 w4 = *(const float4*)(w + k);
      float4 x0 = *(const float4*)&h1n[rb][k];
      float4 x1 = *(const float4*)&h1n[rb + 8][k];
      a0 += x0.x * w4.x + x0.y * w4.y + x0.z * w4.z + x0.w * w4.w;
      a1 += x1.x * w4.x + x1.y * w4.y + x1.z * w4.z + x1.w * w4.w;
    }
    q[rb * 512 + c] = a0;
    q[(rb + 8) * 512 + c] = a1;
  } else {
    const float* w = wmix + (size_t)c * 1024 + 512;
    float a0 = catqpre[rb * 512 + c];
    float a1 = catqpre[(rb + 8) * 512 + c];
#pragma unroll 4
    for (int k = 0; k < 512; k += 4) {
      float4 w4 = *(const float4*)(w + k);
      float4 x0 = *(const float4*)&h1n[rb][k];
      float4 x1 = *(const float4*)&h1n[rb + 8][k];
      a0 += x0.x * w4.x + x0.y * w4.y + x0.z * w4.z + x0.w * w4.w;
      a1 += x1.x * w4.x + x1.y * w4.y + x1.z * w4.z + x1.w * w4.w;
    }
    catq[rb * 512 + c] = a0;
    catq[(rb + 8) * 512 + c] = a1;
  }
}

// K4: both attentions. blocks 0..15: enc attn (batch b). blocks 16..31: cat attn.
__global__ __launch_bounds__(256) void k_attn(const float* __restrict__ enc,
                                              const float* __restrict__ qv,
                                              const float* __restrict__ catq,
                                              const float* __restrict__ catenc,
                                              float* __restrict__ cc,
                                              float* __restrict__ catcc,
                                              float* __restrict__ attnOut, int t) {
  __shared__ float xs[512];
  __shared__ float part[256];
  __shared__ float sc[128];
  __shared__ float redv;
  int tid = threadIdx.x;
  if (blockIdx.x < 16) {
    int b = blockIdx.x;
    for (int i = tid; i < 512; i += 256) xs[i] = qv[b * 512 + i];
    __syncthreads();
    {
      int s = tid & 127, hf = tid >> 7;
      const float* er = enc + ((size_t)(s * 16 + b) * 512) + hf * 256;
      const float* qr = xs + hf * 256;
      float a = 0.f;
#pragma unroll 4
      for (int k = 0; k < 256; k += 4) {
        float4 e = *(const float4*)(er + k);
        a += e.x * qr[k] + e.y * qr[k + 1] + e.z * qr[k + 2] + e.w * qr[k + 3];
      }
      part[tid] = a;
    }
    __syncthreads();
    if (tid < 128) sc[tid] = part[tid] + part[tid + 128];
    __syncthreads();
    if (tid < 64) {
      float m = fmaxf(sc[tid], sc[tid + 64]);
      m = wave_max64(m);
      if (tid == 0) redv = m;
    }
    __syncthreads();
    if (tid < 128) sc[tid] = expf(sc[tid] - redv);
    __syncthreads();
    if (tid < 64) {
      float s2 = sc[tid] + sc[tid + 64];
      s2 = wave_sum64(s2);
      if (tid == 0) redv = 1.0f / s2;
    }
    __syncthreads();
    if (tid < 128) sc[tid] *= redv;
    __syncthreads();
    float a0 = 0.f, a1 = 0.f;
    for (int s2 = 0; s2 < 128; ++s2) {
      const float* er = enc + (size_t)(s2 * 16 + b) * 512;
      float w = sc[s2];
      a0 += w * er[tid];
      a1 += w * er[tid + 256];
    }
    cc[b * 512 + tid] = a0;
    cc[b * 512 + tid + 256] = a1;
  } else {
    int b = blockIdx.x - 16;
    for (int i = tid; i < 512; i += 256) xs[i] = catq[b * 512 + i];
    __syncthreads();
    {
      int k = tid & 63, qt = tid >> 6;
      const float* cr = catenc + ((size_t)(b * 64 + k) * 512) + qt * 128;
      const float* qr = xs + qt * 128;
      float a = 0.f;
#pragma unroll 4
      for (int kk = 0; kk < 128; kk += 4) {
        float4 e = *(const float4*)(cr + kk);
        a += e.x * qr[kk] + e.y * qr[kk + 1] + e.z * qr[kk + 2] + e.w * qr[kk + 3];
      }
      part[tid] = a;
    }
    __syncthreads();
    if (tid < 64) {
      float v = part[tid] + part[tid + 64] + part[tid + 128] + part[tid + 192];
      sc[tid] = v;
      float m = wave_max64(v);
      if (tid == 0) redv = m;
    }
    __syncthreads();
    if (tid < 64) {
      float e = expf(sc[tid] - redv);
      sc[tid] = e;
      float s2 = wave_sum64(e);
      if (tid == 0) redv = 1.0f / s2;
    }
    __syncthreads();
    if (tid < 64) {
      sc[tid] *= redv;
      attnOut[((size_t)b * T + t) * 64 + tid] = sc[tid];
    }
    __syncthreads();
    float a0 = 0.f, a1 = 0.f;
    for (int k2 = 0; k2 < 64; ++k2) {
      const float* cr = catenc + (size_t)(b * 64 + k2) * 512;
      float w = sc[k2];
      a0 += w * cr[tid];
      a1 += w * cr[tid + 256];
    }
    catcc[b * 512 + tid] = a0;
    catcc[b * 512 + tid + 256] = a1;
  }
}

// K5: opn = tanh([cc, decout, catcc] @ linout^T); write ops[t]
__global__ __launch_bounds__(256) void k_dec5(const float* __restrict__ cc,
                                              const float* __restrict__ decout,
                                              const float* __restrict__ catcc,
                                              const float* __restrict__ Wl,
                                              float* __restrict__ ops, int t) {
  int tid = threadIdx.x;
  int c = blockIdx.x * 32 + (tid & 31);
  int rb = tid >> 5;
  const float* w = Wl + (size_t)c * 1536;
  float a0 = 0.f, a1 = 0.f;
  {
    const float* s0 = cc + rb * 512;
    const float* s1 = cc + (rb + 8) * 512;
#pragma unroll 4
    for (int k = 0; k < 512; k += 4) {
      float4 w4 = *(const float4*)(w + k);
      a0 += s0[k] * w4.x + s0[k + 1] * w4.y + s0[k + 2] * w4.z + s0[k + 3] * w4.w;
      a1 += s1[k] * w4.x + s1[k + 1] * w4.y + s1[k + 2] * w4.z + s1[k + 3] * w4.w;
    }
  }
  {
    const float* s0 = decout + rb * 512;
    const float* s1 = decout + (rb + 8) * 512;
#pragma unroll 4
    for (int k = 0; k < 512; k += 4) {
      float4 w4 = *(const float4*)(w + 512 + k);
      a0 += s0[k] * w4.x + s0[k + 1] * w4.y + s0[k + 2] * w4.z + s0[k + 3] * w4.w;
      a1 += s1[k] * w4.x + s1[k + 1] * w4.y + s1[k + 2] * w4.z + s1[k + 3] * w4.w;
    }
  }
  {
    const float* s0 = catcc + rb * 512;
    const float* s1 = catcc + (rb + 8) * 512;
#pragma unroll 4
    for (int k = 0; k < 512; k += 4) {
      float4 w4 = *(const float4*)(w + 1024 + k);
      a0 += s0[k] * w4.x + s0[k + 1] * w4.y + s0[k + 2] * w4.z + s0[k + 3] * w4.w;
      a1 += s1[k] * w4.x + s1[k + 1] * w4.y + s1[k + 2] * w4.z + s1[k + 3] * w4.w;
    }
  }
  ops[(size_t)(t * 16 + rb) * 512 + c] = tanhf(a0);
  ops[(size_t)(t * 16 + rb + 8) * 512 + c] = tanhf(a1);
}

extern "C" void kernel_launch(void* const* d_in, const int* in_sizes, int n_in,
                              void* d_out, int out_size, void* d_ws, size_t ws_size,
                              hipStream_t stream) {
  (void)in_sizes; (void)n_in; (void)out_size; (void)ws_size;
  const int* inp      = (const int*)d_in[0];
  const int* catvec   = (const int*)d_in[1];
  const int* outtok   = (const int*)d_in[2];
  const float* encemb = (const float*)d_in[3];
  const float* decemb = (const float*)d_in[4];
  const float* catembW= (const float*)d_in[5];
  const float* encWih = (const float*)d_in[6];
  const float* encWhh = (const float*)d_in[7];
  const float* encB   = (const float*)d_in[8];
  const float* decWih0= (const float*)d_in[9];
  const float* decWih1= (const float*)d_in[10];
  const float* decWhh = (const float*)d_in[11];
  const float* decB   = (const float*)d_in[12];
  const float* lininW = (const float*)d_in[13];
  const float* linoutW= (const float*)d_in[14];
  const float* stepdW = (const float*)d_in[15];
  const float* mixW   = (const float*)d_in[16];
  const float* genW   = (const float*)d_in[17];
  const float* genB   = (const float*)d_in[18];
  float* out = (float*)d_out;

  float* ws = (float*)d_ws;
  size_t o = 0;
  auto alloc = [&](size_t n) { float* p = ws + o; o += n; return p; };
  // ---- zero-initialized region (one memset) ----
  float* hping  = alloc(LAY * 2 * 8192);  // [l][par][16][512]
  float* cbufE  = alloc(LAY * 8192);      // [l][16][512]
  float* opzero = alloc(8192);
  size_t zeroFloats = o;
  // ---- scratch ----
  float* xemb   = alloc(1048576);  // [2048][512]
  float* y0     = alloc(1048576);
  float* encY   = alloc(1048576);  // layer-1 output == attention memory
  float* xWb    = alloc(4194304);  // [2048][2048]; reused for dtW
  float* h0all  = alloc(16384);    // [2][16][512]
  float* c0all  = alloc(16384);
  float* e2c    = alloc(8192);
  float* cqpre  = alloc(8192);
  float* catenc = alloc(524288);   // [16][64][512]
  float* demb   = alloc(1048576);
  float* g0     = alloc(32768);    // [16][2048]
  float* g1     = alloc(32768);
  float* cping  = alloc(LAY * 2 * 8192);  // [l][par][16][512]
  float* h0buf  = alloc(8192);
  float* h1buf  = alloc(8192);
  float* qb     = alloc(8192);
  float* cqb    = alloc(8192);
  float* ccb    = alloc(8192);
  float* cccb   = alloc(8192);
  float* ops    = alloc(1048576);  // [2048][512] rows t*16+b
  float* dtW    = xWb;             // reuse (encoder done before decoder precompute)

  hipMemsetAsync((void*)ws, 0, zeroFloats * sizeof(float), stream);
  k_embed_enc<<<1024, 256, 0, stream>>>(inp, encemb, xemb);
  k_embed_dec<<<1024, 256, 0, stream>>>(outtok, decemb, demb);
  k_catemb<<<512, 256, 0, stream>>>(catvec, catembW, catenc);

  // ---- encoder ----
  for (int l = 0; l < LAY; ++l) {
    const float* xin = (l == 0) ? xemb : y0;
    float* yout = (l == 0) ? y0 : encY;
    k_gemm<0><<<dim3(32, 32), 256, 0, stream>>>(xin, 512, encWih + (size_t)l * 1048576, 512,
                                                encB + l * 2048, xWb, 2048, 2048, 2048, 512);
    for (int tt = 0; tt < S; ++tt)
      k_enc_step<<<32, 256, 0, stream>>>(xWb, encWhh + (size_t)l * 524288,
                                         hping + l * 16384, cbufE + l * 8192, yout,
                                         h0all + l * 8192, c0all + l * 8192, tt);
  }

  // enc2cat = reshape(h0,(B, 2*H)) @ stepdW^T ; catq_pre = enc2cat @ mixW[:, :512]^T
  k_gemm<0><<<dim3(8, 1), 256, 0, stream>>>(h0all, 1024, stepdW, 1024, nullptr, e2c, 512, 16, 512, 1024);
  k_gemm<0><<<dim3(8, 1), 256, 0, stream>>>(e2c, 512, mixW, 1024, nullptr, cqpre, 512, 16, 512, 512);
  k_init_dec<<<32, 256, 0, stream>>>(h0all, c0all, h0buf, h1buf, cping, cping + 16384);
  // dtW = demb @ Wih0[:, :512]^T + dec_b[0]
  k_gemm<0><<<dim3(32, 32), 256, 0, stream>>>(demb, 512, decWih0, 1024, decB, dtW, 2048, 2048, 2048, 512);

  const float* whh0 = decWhh;
  const float* whh1 = decWhh + (size_t)2048 * 512;
  float* attnOut = out + (size_t)B * T * V;
  for (int t = 0; t < T; ++t) {
    const float* opPrev = (t == 0) ? opzero : ops + (size_t)(t - 1) * 8192;
    k_dec1<<<64, 256, 0, stream>>>(dtW, decWih0, whh0, opPrev, h0buf, g0, t);
    k_dec2<<<64, 256, 0, stream>>>(cping, g0, decWih1, whh1, decB + 2048, h1buf, g1, h0buf, t);
    k_dec3<<<32, 256, 0, stream>>>(cping + 16384, g1, lininW, mixW, cqpre, h1buf, qb, cqb, t);
    k_attn<<<32, 256, 0, stream>>>(encY, qb, cqb, catenc, ccb, cccb, attnOut, t);
    k_dec5<<<16, 256, 0, stream>>>(ccb, h1buf, cccb, linoutW, ops, t);
  }

  // logits = ops @ gen_W^T + gen_b, written as [b][t][v]
  k_gemm<1><<<dim3(V / 64, 32), 256, 0, stream>>>(ops, 512, genW, 512, genB, out, 0, 2048, V, 512);
}